// Round 14
// baseline (803.861 us; speedup 1.0000x reference)
//
#include <hip/hip_runtime.h>
#include <math.h>

#define PPP 20000   // paths
#define TT  30      // max timesteps
#define SS  1000    // samples
#define VNT 10000   // non-terminal vocab
#define PB  32      // paths per LSTM block
#define HSTR 152    // LDS row stride (ushorts): 304B, 16B-aligned

typedef __attribute__((ext_vector_type(8))) short short8;
typedef __attribute__((ext_vector_type(4))) float float4v;
typedef unsigned short ushort;
typedef unsigned int uint;

#define NLOG2E  -1.442695040888963f   // -log2(e): fold for sigmoid gates
#define N2LOG2E -2.885390081777927f   // -2log2(e): fold for tanh gate

__device__ __forceinline__ ushort f2bf(float x) {
    uint u = __builtin_bit_cast(uint, x);
    uint r = (u + 0x7fffu + ((u >> 16) & 1u)) >> 16;
    return (ushort)r;
}
__device__ __forceinline__ float bf2f(ushort h) {
    uint u = ((uint)h) << 16;
    return __builtin_bit_cast(float, u);
}
// pre-scaled activations: input already multiplied by -log2e (sig) / -2log2e (tanh)
__device__ __forceinline__ float fsig_s(float zs) {
    return __builtin_amdgcn_rcpf(1.f + __builtin_amdgcn_exp2f(zs));
}
__device__ __forceinline__ float ftanh_s(float zs) {
    return fmaf(2.f, __builtin_amdgcn_rcpf(1.f + __builtin_amdgcn_exp2f(zs)), -1.f);
}
__device__ __forceinline__ float ftanh(float x) {
    return ftanh_s(x * N2LOG2E);
}

// ---------------- counting sort (DESCENDING) --------------------------------
// NOTE: k_hist MUST be a separate kernel from the bins-zeroing (frag_kernel):
// fusing them raced zero vs atomicAdd across blocks (R13 crash).

__global__ void k_hist(const int* __restrict__ len, int* __restrict__ bins,
                       float* __restrict__ scores) {
    int p = blockIdx.x * 256 + threadIdx.x;
    if (p < PPP) { atomicAdd(&bins[len[p] - 1], 1); scores[p] = 0.f; }
}
__global__ void k_scan(const int* __restrict__ bins, int* __restrict__ cur) {
    if (threadIdx.x == 0 && blockIdx.x == 0) {
        int ofs = 0;
        for (int l = TT - 1; l >= 0; l--) { cur[l] = ofs; ofs += bins[l]; }
    }
}
__global__ void k_scatter(const int* __restrict__ len, int* __restrict__ cur,
                          int* __restrict__ order) {
    int p = blockIdx.x * 256 + threadIdx.x;
    if (p < PPP) {
        int pos = atomicAdd(&cur[len[p] - 1], 1);
        order[pos] = p;
    }
}

// ---------------- fused fragment precompute (+ bins zero) -------------------
// U/W frags get the per-gate activation scale FOLDED IN (i,f,o: -log2e;
// g: -2log2e). slots: [0,16384) ufrag, [16384,32768) wfrag, [32768,38912) pfrag.

__global__ __launch_bounds__(256) void frag_kernel(
    const float* __restrict__ Uf, const float* __restrict__ Ub,
    const float* __restrict__ Wf, const float* __restrict__ Wb,
    const float* __restrict__ proj,
    ushort* __restrict__ Ufrag, ushort* __restrict__ Wfrag,
    ushort* __restrict__ pfrag, int* __restrict__ bins)
{
    if (blockIdx.x == 0 && threadIdx.x < 32) bins[threadIdx.x] = 0;

    const float gsc[4] = {NLOG2E, NLOG2E, N2LOG2E, NLOG2E};
    int gs = blockIdx.x * 256 + threadIdx.x;     // 0..38911
    if (gs < 16384) {                            // ufrag
        int d = gs >> 13, s = gs & 8191;
        const float* U = d ? Ub : Uf;
        int lane = s & 63, kb = (s >> 6) & 3, g = (s >> 8) & 3, w = s >> 10;
        int krow = kb * 32 + (lane >> 4) * 8;
        int col  = g * 128 + w * 16 + (lane & 15);
        float sc = gsc[g];
        ushort* dst = Ufrag + (size_t)gs * 8;
#pragma unroll
        for (int j = 0; j < 8; j++)
            dst[j] = f2bf(U[(size_t)(krow + j) * 512 + col] * sc);
    } else if (gs < 32768) {                     // wfrag
        int t = gs - 16384;
        int d = t >> 13, s = t & 8191;
        const float* W = d ? Wb : Wf;
        int lane = s & 63, kb = (s >> 6) & 3, nt = s >> 8;
        int krow = kb * 32 + (lane >> 4) * 8;
        int col  = nt * 16 + (lane & 15);
        float sc = gsc[col >> 7];
        ushort* dst = Wfrag + (size_t)t * 8;
#pragma unroll
        for (int j = 0; j < 8; j++)
            dst[j] = f2bf(W[(size_t)(krow + j) * 512 + col] * sc);
    } else {                                     // pfrag (no scaling)
        int s = gs - 32768;                      // 0..6143
        int lane = s & 63;
        int kb = (s >> 6) % 12;
        int nt = s / 768;
        int krow = kb * 32 + (lane >> 4) * 8;
        int col  = nt * 16 + (lane & 15);
        ushort* dst = pfrag + (size_t)s * 8;
#pragma unroll
        for (int j = 0; j < 8; j++)
            dst[j] = f2bf(proj[(size_t)(krow + j) * 128 + col]);
    }
}

// ---------------- Zx = emb @ W + b via MFMA -> bf16 gather layout -----------

__global__ __launch_bounds__(512) void zx_kernel(
    const float* __restrict__ emb,
    const ushort* __restrict__ Wfrag,
    const float* __restrict__ bf, const float* __restrict__ bb,
    ushort* __restrict__ Zall)
{
    const float gsc[4] = {NLOG2E, NLOG2E, N2LOG2E, NLOG2E};
    const int dir = blockIdx.y;
    const ushort* WfD = Wfrag + (size_t)dir * 65536;
    const float* bias = dir ? bb : bf;
    ushort* Z = Zall + (size_t)dir * VNT * 512;

    __shared__ union {
        ushort At[64][HSTR];   // A tile: 64 tokens x 128 k (bf16)
        ushort Zt[64][520];    // C bounce: 64 tokens x 512 cols (bf16)
    } sm;

    const int tid  = threadIdx.x;
    const int w    = tid >> 6;
    const int lane = tid & 63;
    const int quad = lane >> 4;
    const int l    = lane & 15;
    const int tok0 = blockIdx.x * 64;

    {
        const int p = tid >> 3, ch = tid & 7;
        int tok = tok0 + p; if (tok > VNT - 1) tok = VNT - 1;
        const float4* src = (const float4*)(emb + (size_t)tok * 128 + ch * 16);
        ushort v[16];
#pragma unroll
        for (int q = 0; q < 4; q++) {
            float4 f = src[q];
            v[q * 4 + 0] = f2bf(f.x); v[q * 4 + 1] = f2bf(f.y);
            v[q * 4 + 2] = f2bf(f.z); v[q * 4 + 3] = f2bf(f.w);
        }
        *(int4*)&sm.At[p][ch * 16]     = *(const int4*)&v[0];
        *(int4*)&sm.At[p][ch * 16 + 8] = *(const int4*)&v[8];
    }

    short8 bq[4][4];   // [nt4][kb]
#pragma unroll
    for (int nt4 = 0; nt4 < 4; nt4++)
#pragma unroll
        for (int kb = 0; kb < 4; kb++)
            bq[nt4][kb] = *(const short8*)(WfD + (size_t)(((w * 4 + nt4) * 4 + kb) * 64 + lane) * 8);

    __syncthreads();

    float4v acc[4][4];     // [mt][nt4]
#pragma unroll
    for (int mt = 0; mt < 4; mt++)
#pragma unroll
        for (int nt4 = 0; nt4 < 4; nt4++) {
            float4v z4 = {0.f, 0.f, 0.f, 0.f};
            acc[mt][nt4] = z4;
        }

#pragma unroll
    for (int kb = 0; kb < 4; kb++) {
        short8 af[4];
#pragma unroll
        for (int mt = 0; mt < 4; mt++)
            af[mt] = *(const short8*)&sm.At[mt * 16 + l][kb * 32 + quad * 8];
#pragma unroll
        for (int nt4 = 0; nt4 < 4; nt4++)
#pragma unroll
            for (int mt = 0; mt < 4; mt++)
                acc[mt][nt4] = __builtin_amdgcn_mfma_f32_16x16x32_bf16(
                    af[mt], bq[nt4][kb], acc[mt][nt4], 0, 0, 0);
    }

    float bv[4];
#pragma unroll
    for (int nt4 = 0; nt4 < 4; nt4++) {
        int col = (w * 4 + nt4) * 16 + l;
        bv[nt4] = bias[col] * gsc[col >> 7];
    }

    __syncthreads();   // all At reads done; union switches to Zt

#pragma unroll
    for (int mt = 0; mt < 4; mt++)
#pragma unroll
        for (int r = 0; r < 4; r++) {
            const int p = mt * 16 + quad * 4 + r;
#pragma unroll
            for (int nt4 = 0; nt4 < 4; nt4++)
                sm.Zt[p][(w * 4 + nt4) * 16 + l] = f2bf(acc[mt][nt4][r] + bv[nt4]);
        }
    __syncthreads();

#pragma unroll
    for (int i = 0; i < 16; i++) {
        int s = i * 512 + tid;          // 0..8191
        int pt = s >> 7;                // token row 0..63
        int u  = s & 127;
        int tok = tok0 + pt;
        if (tok < VNT) {
            ushort v[4];
#pragma unroll
            for (int g = 0; g < 4; g++)
                v[g] = sm.Zt[pt][g * 128 + u];
            *(uint2*)(Z + (size_t)tok * 512 + u * 4) = *(const uint2*)v;
        }
    }
}

// ---------------- MFMA LSTM (32 paths/block, zv pipelined, 3 blocks/CU) -----
// __launch_bounds__(512,6): 6 waves/EU -> VGPR<=80 -> 3 co-resident blocks.

__global__ __launch_bounds__(512, 6) void lstm_kernel(
    const ushort* __restrict__ Zall,
    const ushort* __restrict__ Ufrag,
    const int* __restrict__ path_elements, const int* __restrict__ path_lengths,
    const int* __restrict__ order,
    ushort* __restrict__ h_out)   // bf16 [2][P][128]
{
    const int dir = blockIdx.y;
    const ushort* ZxD = Zall + (size_t)dir * VNT * 512;
    const ushort* UfD = Ufrag + (size_t)dir * 65536;

    __shared__ ushort hp[2][PB][HSTR]; // bf16 h planes (A-layout)
    __shared__ int s_tok[TT][PB];      // pre-shifted byte offsets (tok<<10)
    __shared__ int s_pid[PB];
    __shared__ int s_len[PB];

    const int tid  = threadIdx.x;
    const int w    = tid >> 6;         // wave 0..7
    const int lane = tid & 63;
    const int quad = lane >> 4;
    const int l    = lane & 15;

    if (tid < PB) {
        int idx = blockIdx.x * PB + tid;
        if (idx > PPP - 1) idx = PPP - 1;
        int pid = order[idx];
        s_pid[tid] = pid;
        s_len[tid] = path_lengths[pid];
    }
    for (int i = tid; i < PB * HSTR; i += 512) ((uint*)&hp[0][0][0])[i] = 0;
    __syncthreads();

    for (int i = tid; i < PB * TT; i += 512) {
        int p = i & (PB - 1), t = i >> 5;
        s_tok[t][p] = path_elements[(size_t)s_pid[p] * TT + t] << 10;  // *1024B
    }

    short8 bfrag[4][4];
#pragma unroll
    for (int g = 0; g < 4; g++)
#pragma unroll
        for (int kb = 0; kb < 4; kb++)
            bfrag[g][kb] = *(const short8*)(UfD + (size_t)(((w * 4 + g) * 4 + kb) * 64 + lane) * 8);

    __syncthreads();

    const int maxLen = s_len[0];       // descending sort
    const int myoff  = (w * 16 + l) * 8;
    const char* Zbase = (const char*)ZxD;

    // min length over my 8 rows (largest p I own -> shortest path)
    int lenMin = s_len[16 + quad * 4 + 3];

    float c_st[8];
#pragma unroll
    for (int i = 0; i < 8; i++) c_st[i] = 0.f;

    uint2 zvA[8], zvB[8];
    {
        const int t0 = dir ? (maxLen - 1) : 0;
#pragma unroll
        for (int mt = 0; mt < 2; mt++)
#pragma unroll
            for (int r = 0; r < 4; r++) {
                int off = s_tok[t0][mt * 16 + quad * 4 + r];
                zvA[mt * 4 + r] = *(const uint2*)(Zbase + off + myoff);
            }
    }

    auto stepBody = [&](int step, uint2 (&zvC)[8], uint2 (&zvN)[8]) {
        const int cu = step & 1, nx = cu ^ 1;
        const int t = dir ? (maxLen - 1 - step) : step;

        // acc preload: C = Zx contribution (bf16->f32), arrived last step
        float4v acc[2][4];             // [mt][g]
#pragma unroll
        for (int mt = 0; mt < 2; mt++)
#pragma unroll
            for (int r = 0; r < 4; r++) {
                const uint2 z2 = zvC[mt * 4 + r];
                acc[mt][0][r] = bf2f((ushort)(z2.x & 0xffff));
                acc[mt][1][r] = bf2f((ushort)(z2.x >> 16));
                acc[mt][2][r] = bf2f((ushort)(z2.y & 0xffff));
                acc[mt][3][r] = bf2f((ushort)(z2.y >> 16));
            }

        // prefetch next step's Zx (covered by MFMA + gating + barrier)
        {
            const int stepn = (step + 1 < maxLen) ? step + 1 : step;
            const int tn = dir ? (maxLen - 1 - stepn) : stepn;
#pragma unroll
            for (int mt = 0; mt < 2; mt++)
#pragma unroll
                for (int r = 0; r < 4; r++) {
                    int off = s_tok[tn][mt * 16 + quad * 4 + r];
                    zvN[mt * 4 + r] = *(const uint2*)(Zbase + off + myoff);
                }
        }

#pragma unroll
        for (int kb = 0; kb < 4; kb++) {
            short8 af[2];
#pragma unroll
            for (int mt = 0; mt < 2; mt++)
                af[mt] = *(const short8*)&hp[cu][mt * 16 + l][kb * 32 + quad * 8];
#pragma unroll
            for (int g = 0; g < 4; g++)
#pragma unroll
                for (int mt = 0; mt < 2; mt++)
                    acc[mt][g] = __builtin_amdgcn_mfma_f32_16x16x32_bf16(
                        af[mt], bfrag[g][kb], acc[mt][g], 0, 0, 0);
        }

        if (t < lenMin) {
            // fast path: all my 8 paths valid
#pragma unroll
            for (int mt = 0; mt < 2; mt++)
#pragma unroll
                for (int r = 0; r < 4; r++) {
                    const int p = mt * 16 + quad * 4 + r;
                    float ig = fsig_s(acc[mt][0][r]);
                    float fg = fsig_s(acc[mt][1][r]);
                    float gg = ftanh_s(acc[mt][2][r]);
                    float og = fsig_s(acc[mt][3][r]);
                    float cn = fg * c_st[mt * 4 + r] + ig * gg;
                    float hn = og * ftanh(cn);
                    c_st[mt * 4 + r] = cn;
                    hp[nx][p][w * 16 + l] = f2bf(hn);
                }
        } else {
#pragma unroll
            for (int mt = 0; mt < 2; mt++)
#pragma unroll
                for (int r = 0; r < 4; r++) {
                    const int p = mt * 16 + quad * 4 + r;
                    const bool valid = t < s_len[p];
                    const ushort hold = hp[cu][p][w * 16 + l];
                    float ig = fsig_s(acc[mt][0][r]);
                    float fg = fsig_s(acc[mt][1][r]);
                    float gg = ftanh_s(acc[mt][2][r]);
                    float og = fsig_s(acc[mt][3][r]);
                    float cn = fg * c_st[mt * 4 + r] + ig * gg;
                    float hn = og * ftanh(cn);
                    if (valid) c_st[mt * 4 + r] = cn;
                    hp[nx][p][w * 16 + l] = valid ? f2bf(hn) : hold;
                }
        }
        __syncthreads();
    };

    for (int step = 0; step < maxLen; step += 2) {
        stepBody(step, zvA, zvB);
        if (step + 1 < maxLen) stepBody(step + 1, zvB, zvA);
    }

    // epilogue: final plane -> bf16 h_out; thread -> path pg, cols ch*8..+7
    {
        const int fin = maxLen & 1;
        const int pg = tid >> 4;       // 0..31
        const int ch = tid & 15;       // 0..15 -> 8 cols
        ushort* dst = h_out + ((size_t)dir * PPP + s_pid[pg]) * 128 + ch * 8;
        *(int4*)dst = *(const int4*)&hp[fin][pg][ch * 8];
    }
}

// ---------------- MFMA projection + fused attention scores -----------------

__global__ __launch_bounds__(512) void proj_kernel(
    const float* __restrict__ leaf, const ushort* __restrict__ hbuf,
    const ushort* __restrict__ pfrag, const float* __restrict__ att,
    const int* __restrict__ leaf_idxs,
    float* __restrict__ full, float* __restrict__ scores)
{
    __shared__ ushort Vb[64][400];     // bf16, 16B-aligned rows
    __shared__ int s_lidx[64][2];

    const int tid  = threadIdx.x;
    const int w    = tid >> 6;
    const int lane = tid & 63;
    const int quad = lane >> 4;
    const int l    = lane & 15;
    const int p0   = blockIdx.x * 64;

    if (tid < 128) {
        int p = tid >> 1;
        int pg = p0 + p; if (pg > PPP - 1) pg = PPP - 1;
        s_lidx[p][tid & 1] = leaf_idxs[(size_t)pg * 2 + (tid & 1)];
    }
    __syncthreads();

    for (int s = tid; s < 64 * 192; s += 512) {
        int p = s / 192, cp = s % 192;
        int c = cp * 2;
        int pg = p0 + p; if (pg > PPP - 1) pg = PPP - 1;
        uint val;
        if (c < 128) {
            const float* src = leaf + (size_t)s_lidx[p][c >> 6] * 64 + (c & 63);
            float2 f = *(const float2*)src;
            val = (uint)f2bf(f.x) | ((uint)f2bf(f.y) << 16);
        } else {
            const ushort* src = hbuf + ((size_t)(c < 256 ? 0 : 1) * PPP + pg) * 128 + (c & 127);
            val = *(const uint*)src;
        }
        *(uint*)&Vb[p][c] = val;
    }

    short8 bq[12];
#pragma unroll
    for (int kb = 0; kb < 12; kb++)
        bq[kb] = *(const short8*)(pfrag + ((size_t)w * 768 + kb * 64 + lane) * 8);

    __syncthreads();

    float4v acc[4];
#pragma unroll
    for (int mt = 0; mt < 4; mt++) {
        float4v z4 = {0.f, 0.f, 0.f, 0.f};
        acc[mt] = z4;
    }

#pragma unroll
    for (int kb = 0; kb < 12; kb++) {
#pragma unroll
        for (int mt = 0; mt < 4; mt++) {
            short8 af = *(const short8*)&Vb[mt * 16 + l][kb * 32 + quad * 8];
            acc[mt] = __builtin_amdgcn_mfma_f32_16x16x32_bf16(af, bq[kb], acc[mt], 0, 0, 0);
        }
    }

    const int col = w * 16 + l;
    const float attc = att[col];
#pragma unroll
    for (int mt = 0; mt < 4; mt++)
#pragma unroll
        for (int r = 0; r < 4; r++) {
            int row = mt * 16 + quad * 4 + r;
            int pg = p0 + row;
            float v = acc[mt][r];
            if (pg < PPP) full[(size_t)pg * 128 + col] = v;
            float part = v * attc;
            part += __shfl_xor(part, 1);
            part += __shfl_xor(part, 2);
            part += __shfl_xor(part, 4);
            part += __shfl_xor(part, 8);
            if (l == 0 && pg < PPP) atomicAdd(&scores[pg], part);
        }
}

// ---------------- segment softmax + weighted sum (512 threads) --------------

__global__ __launch_bounds__(512) void seg_kernel(
    const float* __restrict__ scores, const float* __restrict__ full,
    const int* __restrict__ seg, float* __restrict__ out)
{
    const int s = blockIdx.x;
    const int tid = threadIdx.x;

    int lo = 0, hi = PPP;
    while (lo < hi) { int mid = (lo + hi) >> 1; if (seg[mid] < s) lo = mid + 1; else hi = mid; }
    const int start = lo;
    lo = start; hi = PPP;
    while (lo < hi) { int mid = (lo + hi) >> 1; if (seg[mid] < s + 1) lo = mid + 1; else hi = mid; }
    const int end = lo;

    if (start >= end) {
        if (tid < 128) out[(size_t)s * 128 + tid] = 0.f;
        return;
    }

    __shared__ float red[512];

    float mx = -1e30f;
    for (int i = start + tid; i < end; i += 512) mx = fmaxf(mx, scores[i]);
    red[tid] = mx; __syncthreads();
    for (int off = 256; off > 0; off >>= 1) {
        if (tid < off) red[tid] = fmaxf(red[tid], red[tid + off]);
        __syncthreads();
    }
    mx = red[0]; __syncthreads();

    float den = 0.f;
    for (int i = start + tid; i < end; i += 512) den += __expf(scores[i] - mx);
    red[tid] = den; __syncthreads();
    for (int off = 256; off > 0; off >>= 1) {
        if (tid < off) red[tid] += red[tid + off];
        __syncthreads();
    }
    den = red[0]; __syncthreads();

    const int col = tid & 127;
    const int pp  = tid >> 7;         // 0..3: 4 paths in flight
    float acc = 0.f;
    for (int i = start + pp; i < end; i += 4)
        acc = fmaf(__expf(scores[i] - mx), full[(size_t)i * 128 + col], acc);
    red[tid] = acc; __syncthreads();
    if (tid < 128)
        out[(size_t)s * 128 + tid] =
            (red[tid] + red[tid + 128] + red[tid + 256] + red[tid + 384]) / den;
}

// ---------------- launch ---------------------------------------------------

extern "C" void kernel_launch(void* const* d_in, const int* in_sizes, int n_in,
                              void* d_out, int out_size, void* d_ws, size_t ws_size,
                              hipStream_t stream) {
    (void)in_sizes; (void)n_in; (void)out_size; (void)ws_size;

    const float* leaf = (const float*)d_in[0];
    const float* emb  = (const float*)d_in[1];
    const float* Wf   = (const float*)d_in[2];
    const float* Uf   = (const float*)d_in[3];
    const float* bf   = (const float*)d_in[4];
    const float* Wb   = (const float*)d_in[5];
    const float* Ub   = (const float*)d_in[6];
    const float* bb   = (const float*)d_in[7];
    const float* proj = (const float*)d_in[8];
    const float* att  = (const float*)d_in[9];
    const int* path_elements = (const int*)d_in[10];
    const int* path_lengths  = (const int*)d_in[11];
    const int* leaf_idxs     = (const int*)d_in[12];
    const int* seg           = (const int*)d_in[13];
    float* out = (float*)d_out;

    char* ws = (char*)d_ws;
    int*    order  = (int*)ws;                         // 80,000 B
    int*    bins   = (int*)(ws + 80128);
    int*    cur    = (int*)(ws + 80384);
    ushort* Zall   = (ushort*)(ws + 81920);            // 20,480,000
    ushort* Ufrag  = (ushort*)(ws + 20561920);         // 262,144
    ushort* pfrag  = (ushort*)(ws + 20824064);         // 98,304
    ushort* Wfrag  = (ushort*)(ws + 20922368);         // 262,144
    ushort* hbuf   = (ushort*)(ws + 21184512);         // 10,240,000 (bf16)
    float*  full   = (float*)(ws + 31424512);          // 10,240,000
    float*  scores = (float*)(ws + 41664512);          // 80,000

    frag_kernel<<<152, 256, 0, stream>>>(Uf, Ub, Wf, Wb, proj,
                                         Ufrag, Wfrag, pfrag, bins);

    k_hist<<<(PPP + 255) / 256, 256, 0, stream>>>(path_lengths, bins, scores);
    k_scan<<<1, 64, 0, stream>>>(bins, cur);
    k_scatter<<<(PPP + 255) / 256, 256, 0, stream>>>(path_lengths, cur, order);

    dim3 gz((VNT + 63) / 64, 2);
    zx_kernel<<<gz, 512, 0, stream>>>(emb, Wfrag, bf, bb, Zall);

    dim3 g(PPP / PB, 2);
    lstm_kernel<<<g, 512, 0, stream>>>(Zall, Ufrag, path_elements, path_lengths,
                                       order, hbuf);

    proj_kernel<<<(PPP + 63) / 64, 512, 0, stream>>>(leaf, hbuf, pfrag, att,
                                                     leaf_idxs, full, scores);

    seg_kernel<<<SS, 512, 0, stream>>>(scores, full, seg, out);
}

// Round 15
// 360.149 us; speedup vs baseline: 2.2320x; 2.2320x over previous
//
#include <hip/hip_runtime.h>
#include <math.h>

#define PPP 20000   // paths
#define TT  30      // max timesteps
#define SS  1000    // samples
#define VNT 10000   // non-terminal vocab
#define PB  32      // paths per LSTM block
#define HSTR 152    // LDS row stride (ushorts): 304B, 16B-aligned

typedef __attribute__((ext_vector_type(8))) short short8;
typedef __attribute__((ext_vector_type(4))) float float4v;
typedef unsigned short ushort;
typedef unsigned int uint;

#define NLOG2E  -1.442695040888963f   // -log2(e): fold for sigmoid gates
#define N2LOG2E -2.885390081777927f   // -2log2(e): fold for tanh gate

__device__ __forceinline__ ushort f2bf(float x) {
    uint u = __builtin_bit_cast(uint, x);
    uint r = (u + 0x7fffu + ((u >> 16) & 1u)) >> 16;
    return (ushort)r;
}
__device__ __forceinline__ float bf2f(ushort h) {
    uint u = ((uint)h) << 16;
    return __builtin_bit_cast(float, u);
}
// pre-scaled activations: input already multiplied by -log2e (sig) / -2log2e (tanh)
__device__ __forceinline__ float fsig_s(float zs) {
    return __builtin_amdgcn_rcpf(1.f + __builtin_amdgcn_exp2f(zs));
}
__device__ __forceinline__ float ftanh_s(float zs) {
    return fmaf(2.f, __builtin_amdgcn_rcpf(1.f + __builtin_amdgcn_exp2f(zs)), -1.f);
}
__device__ __forceinline__ float ftanh(float x) {
    return ftanh_s(x * N2LOG2E);
}

// ---------------- counting sort (DESCENDING) --------------------------------
// NOTE: k_hist MUST be a separate kernel from the bins-zeroing (frag_kernel):
// fusing them raced zero vs atomicAdd across blocks (R13 crash).

__global__ void k_hist(const int* __restrict__ len, int* __restrict__ bins,
                       float* __restrict__ scores) {
    int p = blockIdx.x * 256 + threadIdx.x;
    if (p < PPP) { atomicAdd(&bins[len[p] - 1], 1); scores[p] = 0.f; }
}
__global__ void k_scan(const int* __restrict__ bins, int* __restrict__ cur) {
    if (threadIdx.x == 0 && blockIdx.x == 0) {
        int ofs = 0;
        for (int l = TT - 1; l >= 0; l--) { cur[l] = ofs; ofs += bins[l]; }
    }
}
__global__ void k_scatter(const int* __restrict__ len, int* __restrict__ cur,
                          int* __restrict__ order) {
    int p = blockIdx.x * 256 + threadIdx.x;
    if (p < PPP) {
        int pos = atomicAdd(&cur[len[p] - 1], 1);
        order[pos] = p;
    }
}

// ---------------- fused fragment precompute (+ bins zero) -------------------
// U/W frags get the per-gate activation scale FOLDED IN (i,f,o: -log2e;
// g: -2log2e). slots: [0,16384) ufrag, [16384,32768) wfrag, [32768,38912) pfrag.

__global__ __launch_bounds__(256) void frag_kernel(
    const float* __restrict__ Uf, const float* __restrict__ Ub,
    const float* __restrict__ Wf, const float* __restrict__ Wb,
    const float* __restrict__ proj,
    ushort* __restrict__ Ufrag, ushort* __restrict__ Wfrag,
    ushort* __restrict__ pfrag, int* __restrict__ bins)
{
    if (blockIdx.x == 0 && threadIdx.x < 32) bins[threadIdx.x] = 0;

    const float gsc[4] = {NLOG2E, NLOG2E, N2LOG2E, NLOG2E};
    int gs = blockIdx.x * 256 + threadIdx.x;     // 0..38911
    if (gs < 16384) {                            // ufrag
        int d = gs >> 13, s = gs & 8191;
        const float* U = d ? Ub : Uf;
        int lane = s & 63, kb = (s >> 6) & 3, g = (s >> 8) & 3, w = s >> 10;
        int krow = kb * 32 + (lane >> 4) * 8;
        int col  = g * 128 + w * 16 + (lane & 15);
        float sc = gsc[g];
        ushort* dst = Ufrag + (size_t)gs * 8;
#pragma unroll
        for (int j = 0; j < 8; j++)
            dst[j] = f2bf(U[(size_t)(krow + j) * 512 + col] * sc);
    } else if (gs < 32768) {                     // wfrag
        int t = gs - 16384;
        int d = t >> 13, s = t & 8191;
        const float* W = d ? Wb : Wf;
        int lane = s & 63, kb = (s >> 6) & 3, nt = s >> 8;
        int krow = kb * 32 + (lane >> 4) * 8;
        int col  = nt * 16 + (lane & 15);
        float sc = gsc[col >> 7];
        ushort* dst = Wfrag + (size_t)t * 8;
#pragma unroll
        for (int j = 0; j < 8; j++)
            dst[j] = f2bf(W[(size_t)(krow + j) * 512 + col] * sc);
    } else {                                     // pfrag (no scaling)
        int s = gs - 32768;                      // 0..6143
        int lane = s & 63;
        int kb = (s >> 6) % 12;
        int nt = s / 768;
        int krow = kb * 32 + (lane >> 4) * 8;
        int col  = nt * 16 + (lane & 15);
        ushort* dst = pfrag + (size_t)s * 8;
#pragma unroll
        for (int j = 0; j < 8; j++)
            dst[j] = f2bf(proj[(size_t)(krow + j) * 128 + col]);
    }
}

// ---------------- Zx = emb @ W + b via MFMA -> bf16 gather layout -----------

__global__ __launch_bounds__(512) void zx_kernel(
    const float* __restrict__ emb,
    const ushort* __restrict__ Wfrag,
    const float* __restrict__ bf, const float* __restrict__ bb,
    ushort* __restrict__ Zall)
{
    const float gsc[4] = {NLOG2E, NLOG2E, N2LOG2E, NLOG2E};
    const int dir = blockIdx.y;
    const ushort* WfD = Wfrag + (size_t)dir * 65536;
    const float* bias = dir ? bb : bf;
    ushort* Z = Zall + (size_t)dir * VNT * 512;

    __shared__ union {
        ushort At[64][HSTR];   // A tile: 64 tokens x 128 k (bf16)
        ushort Zt[64][520];    // C bounce: 64 tokens x 512 cols (bf16)
    } sm;

    const int tid  = threadIdx.x;
    const int w    = tid >> 6;
    const int lane = tid & 63;
    const int quad = lane >> 4;
    const int l    = lane & 15;
    const int tok0 = blockIdx.x * 64;

    {
        const int p = tid >> 3, ch = tid & 7;
        int tok = tok0 + p; if (tok > VNT - 1) tok = VNT - 1;
        const float4* src = (const float4*)(emb + (size_t)tok * 128 + ch * 16);
        ushort v[16];
#pragma unroll
        for (int q = 0; q < 4; q++) {
            float4 f = src[q];
            v[q * 4 + 0] = f2bf(f.x); v[q * 4 + 1] = f2bf(f.y);
            v[q * 4 + 2] = f2bf(f.z); v[q * 4 + 3] = f2bf(f.w);
        }
        *(int4*)&sm.At[p][ch * 16]     = *(const int4*)&v[0];
        *(int4*)&sm.At[p][ch * 16 + 8] = *(const int4*)&v[8];
    }

    short8 bq[4][4];   // [nt4][kb]
#pragma unroll
    for (int nt4 = 0; nt4 < 4; nt4++)
#pragma unroll
        for (int kb = 0; kb < 4; kb++)
            bq[nt4][kb] = *(const short8*)(WfD + (size_t)(((w * 4 + nt4) * 4 + kb) * 64 + lane) * 8);

    __syncthreads();

    float4v acc[4][4];     // [mt][nt4]
#pragma unroll
    for (int mt = 0; mt < 4; mt++)
#pragma unroll
        for (int nt4 = 0; nt4 < 4; nt4++) {
            float4v z4 = {0.f, 0.f, 0.f, 0.f};
            acc[mt][nt4] = z4;
        }

#pragma unroll
    for (int kb = 0; kb < 4; kb++) {
        short8 af[4];
#pragma unroll
        for (int mt = 0; mt < 4; mt++)
            af[mt] = *(const short8*)&sm.At[mt * 16 + l][kb * 32 + quad * 8];
#pragma unroll
        for (int nt4 = 0; nt4 < 4; nt4++)
#pragma unroll
            for (int mt = 0; mt < 4; mt++)
                acc[mt][nt4] = __builtin_amdgcn_mfma_f32_16x16x32_bf16(
                    af[mt], bq[nt4][kb], acc[mt][nt4], 0, 0, 0);
    }

    float bv[4];
#pragma unroll
    for (int nt4 = 0; nt4 < 4; nt4++) {
        int col = (w * 4 + nt4) * 16 + l;
        bv[nt4] = bias[col] * gsc[col >> 7];
    }

    __syncthreads();   // all At reads done; union switches to Zt

#pragma unroll
    for (int mt = 0; mt < 4; mt++)
#pragma unroll
        for (int r = 0; r < 4; r++) {
            const int p = mt * 16 + quad * 4 + r;
#pragma unroll
            for (int nt4 = 0; nt4 < 4; nt4++)
                sm.Zt[p][(w * 4 + nt4) * 16 + l] = f2bf(acc[mt][nt4][r] + bv[nt4]);
        }
    __syncthreads();

#pragma unroll
    for (int i = 0; i < 16; i++) {
        int s = i * 512 + tid;          // 0..8191
        int pt = s >> 7;                // token row 0..63
        int u  = s & 127;
        int tok = tok0 + pt;
        if (tok < VNT) {
            ushort v[4];
#pragma unroll
            for (int g = 0; g < 4; g++)
                v[g] = sm.Zt[pt][g * 128 + u];
            *(uint2*)(Z + (size_t)tok * 512 + u * 4) = *(const uint2*)v;
        }
    }
}

// ---------------- MFMA LSTM (32 paths/block, zv pipelined) ------------------
// (512,2): VGPR 88, no spill, 2 blocks/CU — verified best config (R12).
// (512,6) forced VGPR=40 -> 527MB spill, 3.6x regression (R14). Do not raise.

__global__ __launch_bounds__(512, 2) void lstm_kernel(
    const ushort* __restrict__ Zall,
    const ushort* __restrict__ Ufrag,
    const int* __restrict__ path_elements, const int* __restrict__ path_lengths,
    const int* __restrict__ order,
    ushort* __restrict__ h_out)   // bf16 [2][P][128]
{
    const int dir = blockIdx.y;
    const ushort* ZxD = Zall + (size_t)dir * VNT * 512;
    const ushort* UfD = Ufrag + (size_t)dir * 65536;

    __shared__ ushort hp[2][PB][HSTR]; // bf16 h planes (A-layout)
    __shared__ int s_tok[TT][PB];      // pre-shifted byte offsets (tok<<10)
    __shared__ int s_pid[PB];
    __shared__ int s_len[PB];

    const int tid  = threadIdx.x;
    const int w    = tid >> 6;         // wave 0..7
    const int lane = tid & 63;
    const int quad = lane >> 4;
    const int l    = lane & 15;

    if (tid < PB) {
        int idx = blockIdx.x * PB + tid;
        if (idx > PPP - 1) idx = PPP - 1;
        int pid = order[idx];
        s_pid[tid] = pid;
        s_len[tid] = path_lengths[pid];
    }
    for (int i = tid; i < PB * HSTR; i += 512) ((uint*)&hp[0][0][0])[i] = 0;
    __syncthreads();

    for (int i = tid; i < PB * TT; i += 512) {
        int p = i & (PB - 1), t = i >> 5;
        s_tok[t][p] = path_elements[(size_t)s_pid[p] * TT + t] << 10;  // *1024B
    }

    short8 bfrag[4][4];
#pragma unroll
    for (int g = 0; g < 4; g++)
#pragma unroll
        for (int kb = 0; kb < 4; kb++)
            bfrag[g][kb] = *(const short8*)(UfD + (size_t)(((w * 4 + g) * 4 + kb) * 64 + lane) * 8);

    __syncthreads();

    const int maxLen = s_len[0];       // descending sort
    const int myoff  = (w * 16 + l) * 8;
    const char* Zbase = (const char*)ZxD;

    // min length over my 8 rows (largest p I own -> shortest path)
    int lenMin = s_len[16 + quad * 4 + 3];

    float c_st[8];
#pragma unroll
    for (int i = 0; i < 8; i++) c_st[i] = 0.f;

    uint2 zvA[8], zvB[8];
    {
        const int t0 = dir ? (maxLen - 1) : 0;
#pragma unroll
        for (int mt = 0; mt < 2; mt++)
#pragma unroll
            for (int r = 0; r < 4; r++) {
                int off = s_tok[t0][mt * 16 + quad * 4 + r];
                zvA[mt * 4 + r] = *(const uint2*)(Zbase + off + myoff);
            }
    }

    auto stepBody = [&](int step, uint2 (&zvC)[8], uint2 (&zvN)[8]) {
        const int cu = step & 1, nx = cu ^ 1;
        const int t = dir ? (maxLen - 1 - step) : step;

        // acc preload: C = Zx contribution (bf16->f32), arrived last step
        float4v acc[2][4];             // [mt][g]
#pragma unroll
        for (int mt = 0; mt < 2; mt++)
#pragma unroll
            for (int r = 0; r < 4; r++) {
                const uint2 z2 = zvC[mt * 4 + r];
                acc[mt][0][r] = bf2f((ushort)(z2.x & 0xffff));
                acc[mt][1][r] = bf2f((ushort)(z2.x >> 16));
                acc[mt][2][r] = bf2f((ushort)(z2.y & 0xffff));
                acc[mt][3][r] = bf2f((ushort)(z2.y >> 16));
            }

        // prefetch next step's Zx (covered by MFMA + gating + barrier)
        {
            const int stepn = (step + 1 < maxLen) ? step + 1 : step;
            const int tn = dir ? (maxLen - 1 - stepn) : stepn;
#pragma unroll
            for (int mt = 0; mt < 2; mt++)
#pragma unroll
                for (int r = 0; r < 4; r++) {
                    int off = s_tok[tn][mt * 16 + quad * 4 + r];
                    zvN[mt * 4 + r] = *(const uint2*)(Zbase + off + myoff);
                }
        }

#pragma unroll
        for (int kb = 0; kb < 4; kb++) {
            short8 af[2];
#pragma unroll
            for (int mt = 0; mt < 2; mt++)
                af[mt] = *(const short8*)&hp[cu][mt * 16 + l][kb * 32 + quad * 8];
#pragma unroll
            for (int g = 0; g < 4; g++)
#pragma unroll
                for (int mt = 0; mt < 2; mt++)
                    acc[mt][g] = __builtin_amdgcn_mfma_f32_16x16x32_bf16(
                        af[mt], bfrag[g][kb], acc[mt][g], 0, 0, 0);
        }

        if (t < lenMin) {
            // fast path: all my 8 paths valid
#pragma unroll
            for (int mt = 0; mt < 2; mt++)
#pragma unroll
                for (int r = 0; r < 4; r++) {
                    const int p = mt * 16 + quad * 4 + r;
                    float ig = fsig_s(acc[mt][0][r]);
                    float fg = fsig_s(acc[mt][1][r]);
                    float gg = ftanh_s(acc[mt][2][r]);
                    float og = fsig_s(acc[mt][3][r]);
                    float cn = fg * c_st[mt * 4 + r] + ig * gg;
                    float hn = og * ftanh(cn);
                    c_st[mt * 4 + r] = cn;
                    hp[nx][p][w * 16 + l] = f2bf(hn);
                }
        } else {
#pragma unroll
            for (int mt = 0; mt < 2; mt++)
#pragma unroll
                for (int r = 0; r < 4; r++) {
                    const int p = mt * 16 + quad * 4 + r;
                    const bool valid = t < s_len[p];
                    const ushort hold = hp[cu][p][w * 16 + l];
                    float ig = fsig_s(acc[mt][0][r]);
                    float fg = fsig_s(acc[mt][1][r]);
                    float gg = ftanh_s(acc[mt][2][r]);
                    float og = fsig_s(acc[mt][3][r]);
                    float cn = fg * c_st[mt * 4 + r] + ig * gg;
                    float hn = og * ftanh(cn);
                    if (valid) c_st[mt * 4 + r] = cn;
                    hp[nx][p][w * 16 + l] = valid ? f2bf(hn) : hold;
                }
        }
        __syncthreads();
    };

    for (int step = 0; step < maxLen; step += 2) {
        stepBody(step, zvA, zvB);
        if (step + 1 < maxLen) stepBody(step + 1, zvB, zvA);
    }

    // epilogue: final plane -> bf16 h_out; thread -> path pg, cols ch*8..+7
    {
        const int fin = maxLen & 1;
        const int pg = tid >> 4;       // 0..31
        const int ch = tid & 15;       // 0..15 -> 8 cols
        ushort* dst = h_out + ((size_t)dir * PPP + s_pid[pg]) * 128 + ch * 8;
        *(int4*)dst = *(const int4*)&hp[fin][pg][ch * 8];
    }
}

// ---------------- MFMA projection + fused attention scores -----------------

__global__ __launch_bounds__(512) void proj_kernel(
    const float* __restrict__ leaf, const ushort* __restrict__ hbuf,
    const ushort* __restrict__ pfrag, const float* __restrict__ att,
    const int* __restrict__ leaf_idxs,
    float* __restrict__ full, float* __restrict__ scores)
{
    __shared__ ushort Vb[64][400];     // bf16, 16B-aligned rows
    __shared__ int s_lidx[64][2];

    const int tid  = threadIdx.x;
    const int w    = tid >> 6;
    const int lane = tid & 63;
    const int quad = lane >> 4;
    const int l    = lane & 15;
    const int p0   = blockIdx.x * 64;

    if (tid < 128) {
        int p = tid >> 1;
        int pg = p0 + p; if (pg > PPP - 1) pg = PPP - 1;
        s_lidx[p][tid & 1] = leaf_idxs[(size_t)pg * 2 + (tid & 1)];
    }
    __syncthreads();

    for (int s = tid; s < 64 * 192; s += 512) {
        int p = s / 192, cp = s % 192;
        int c = cp * 2;
        int pg = p0 + p; if (pg > PPP - 1) pg = PPP - 1;
        uint val;
        if (c < 128) {
            const float* src = leaf + (size_t)s_lidx[p][c >> 6] * 64 + (c & 63);
            float2 f = *(const float2*)src;
            val = (uint)f2bf(f.x) | ((uint)f2bf(f.y) << 16);
        } else {
            const ushort* src = hbuf + ((size_t)(c < 256 ? 0 : 1) * PPP + pg) * 128 + (c & 127);
            val = *(const uint*)src;
        }
        *(uint*)&Vb[p][c] = val;
    }

    short8 bq[12];
#pragma unroll
    for (int kb = 0; kb < 12; kb++)
        bq[kb] = *(const short8*)(pfrag + ((size_t)w * 768 + kb * 64 + lane) * 8);

    __syncthreads();

    float4v acc[4];
#pragma unroll
    for (int mt = 0; mt < 4; mt++) {
        float4v z4 = {0.f, 0.f, 0.f, 0.f};
        acc[mt] = z4;
    }

#pragma unroll
    for (int kb = 0; kb < 12; kb++) {
#pragma unroll
        for (int mt = 0; mt < 4; mt++) {
            short8 af = *(const short8*)&Vb[mt * 16 + l][kb * 32 + quad * 8];
            acc[mt] = __builtin_amdgcn_mfma_f32_16x16x32_bf16(af, bq[kb], acc[mt], 0, 0, 0);
        }
    }

    const int col = w * 16 + l;
    const float attc = att[col];
#pragma unroll
    for (int mt = 0; mt < 4; mt++)
#pragma unroll
        for (int r = 0; r < 4; r++) {
            int row = mt * 16 + quad * 4 + r;
            int pg = p0 + row;
            float v = acc[mt][r];
            if (pg < PPP) full[(size_t)pg * 128 + col] = v;
            float part = v * attc;
            part += __shfl_xor(part, 1);
            part += __shfl_xor(part, 2);
            part += __shfl_xor(part, 4);
            part += __shfl_xor(part, 8);
            if (l == 0 && pg < PPP) atomicAdd(&scores[pg], part);
        }
}

// ---------------- segment softmax + weighted sum (512 threads) --------------

__global__ __launch_bounds__(512) void seg_kernel(
    const float* __restrict__ scores, const float* __restrict__ full,
    const int* __restrict__ seg, float* __restrict__ out)
{
    const int s = blockIdx.x;
    const int tid = threadIdx.x;

    int lo = 0, hi = PPP;
    while (lo < hi) { int mid = (lo + hi) >> 1; if (seg[mid] < s) lo = mid + 1; else hi = mid; }
    const int start = lo;
    lo = start; hi = PPP;
    while (lo < hi) { int mid = (lo + hi) >> 1; if (seg[mid] < s + 1) lo = mid + 1; else hi = mid; }
    const int end = lo;

    if (start >= end) {
        if (tid < 128) out[(size_t)s * 128 + tid] = 0.f;
        return;
    }

    __shared__ float red[512];

    float mx = -1e30f;
    for (int i = start + tid; i < end; i += 512) mx = fmaxf(mx, scores[i]);
    red[tid] = mx; __syncthreads();
    for (int off = 256; off > 0; off >>= 1) {
        if (tid < off) red[tid] = fmaxf(red[tid], red[tid + off]);
        __syncthreads();
    }
    mx = red[0]; __syncthreads();

    float den = 0.f;
    for (int i = start + tid; i < end; i += 512) den += __expf(scores[i] - mx);
    red[tid] = den; __syncthreads();
    for (int off = 256; off > 0; off >>= 1) {
        if (tid < off) red[tid] += red[tid + off];
        __syncthreads();
    }
    den = red[0]; __syncthreads();

    const int col = tid & 127;
    const int pp  = tid >> 7;         // 0..3: 4 paths in flight
    float acc = 0.f;
    for (int i = start + pp; i < end; i += 4)
        acc = fmaf(__expf(scores[i] - mx), full[(size_t)i * 128 + col], acc);
    red[tid] = acc; __syncthreads();
    if (tid < 128)
        out[(size_t)s * 128 + tid] =
            (red[tid] + red[tid + 128] + red[tid + 256] + red[tid + 384]) / den;
}

// ---------------- launch ---------------------------------------------------

extern "C" void kernel_launch(void* const* d_in, const int* in_sizes, int n_in,
                              void* d_out, int out_size, void* d_ws, size_t ws_size,
                              hipStream_t stream) {
    (void)in_sizes; (void)n_in; (void)out_size; (void)ws_size;

    const float* leaf = (const float*)d_in[0];
    const float* emb  = (const float*)d_in[1];
    const float* Wf   = (const float*)d_in[2];
    const float* Uf   = (const float*)d_in[3];
    const float* bf   = (const float*)d_in[4];
    const float* Wb   = (const float*)d_in[5];
    const float* Ub   = (const float*)d_in[6];
    const float* bb   = (const float*)d_in[7];
    const float* proj = (const float*)d_in[8];
    const float* att  = (const float*)d_in[9];
    const int* path_elements = (const int*)d_in[10];
    const int* path_lengths  = (const int*)d_in[11];
    const int* leaf_idxs     = (const int*)d_in[12];
    const int* seg           = (const int*)d_in[13];
    float* out = (float*)d_out;

    char* ws = (char*)d_ws;
    int*    order  = (int*)ws;                         // 80,000 B
    int*    bins   = (int*)(ws + 80128);
    int*    cur    = (int*)(ws + 80384);
    ushort* Zall   = (ushort*)(ws + 81920);            // 20,480,000
    ushort* Ufrag  = (ushort*)(ws + 20561920);         // 262,144
    ushort* pfrag  = (ushort*)(ws + 20824064);         // 98,304
    ushort* Wfrag  = (ushort*)(ws + 20922368);         // 262,144
    ushort* hbuf   = (ushort*)(ws + 21184512);         // 10,240,000 (bf16)
    float*  full   = (float*)(ws + 31424512);          // 10,240,000
    float*  scores = (float*)(ws + 41664512);          // 80,000

    frag_kernel<<<152, 256, 0, stream>>>(Uf, Ub, Wf, Wb, proj,
                                         Ufrag, Wfrag, pfrag, bins);

    k_hist<<<(PPP + 255) / 256, 256, 0, stream>>>(path_lengths, bins, scores);
    k_scan<<<1, 64, 0, stream>>>(bins, cur);
    k_scatter<<<(PPP + 255) / 256, 256, 0, stream>>>(path_lengths, cur, order);

    dim3 gz((VNT + 63) / 64, 2);
    zx_kernel<<<gz, 512, 0, stream>>>(emb, Wfrag, bf, bb, Zall);

    dim3 g(PPP / PB, 2);
    lstm_kernel<<<g, 512, 0, stream>>>(Zall, Ufrag, path_elements, path_lengths,
                                       order, hbuf);

    proj_kernel<<<(PPP + 63) / 64, 512, 0, stream>>>(leaf, hbuf, pfrag, att,
                                                     leaf_idxs, full, scores);

    seg_kernel<<<SS, 512, 0, stream>>>(scores, full, seg, out);
}

// Round 16
// 301.854 us; speedup vs baseline: 2.6631x; 1.1931x over previous
//
#include <hip/hip_runtime.h>
#include <math.h>

#define PPP 20000   // paths
#define TT  30      // max timesteps
#define SS  1000    // samples
#define VNT 10000   // non-terminal vocab
#define PB  32      // paths per LSTM block
#define HSTR 152    // LDS row stride (ushorts): 304B, 16B-aligned
#define NSUB 32     // sub-histograms per length bin (atomic contention /32)

typedef __attribute__((ext_vector_type(8))) short short8;
typedef __attribute__((ext_vector_type(4))) float float4v;
typedef unsigned short ushort;
typedef unsigned int uint;

#define NLOG2E  -1.442695040888963f   // -log2(e): fold for sigmoid gates
#define N2LOG2E -2.885390081777927f   // -2log2(e): fold for tanh gate

__device__ __forceinline__ ushort f2bf(float x) {
    uint u = __builtin_bit_cast(uint, x);
    uint r = (u + 0x7fffu + ((u >> 16) & 1u)) >> 16;
    return (ushort)r;
}
__device__ __forceinline__ float bf2f(ushort h) {
    uint u = ((uint)h) << 16;
    return __builtin_bit_cast(float, u);
}
// pre-scaled activations: input already multiplied by -log2e (sig) / -2log2e (tanh)
__device__ __forceinline__ float fsig_s(float zs) {
    return __builtin_amdgcn_rcpf(1.f + __builtin_amdgcn_exp2f(zs));
}
__device__ __forceinline__ float ftanh_s(float zs) {
    return fmaf(2.f, __builtin_amdgcn_rcpf(1.f + __builtin_amdgcn_exp2f(zs)), -1.f);
}
__device__ __forceinline__ float ftanh(float x) {
    return ftanh_s(x * N2LOG2E);
}

// ---------------- fused counting sort (DESCENDING), single block ------------
// One launch replaces hist+scan+scatter. Self-contained in LDS (no global
// bins -> no zero/add race across kernels). Also zeroes scores.

__global__ __launch_bounds__(1024) void sort_kernel(
    const int* __restrict__ len, int* __restrict__ order,
    float* __restrict__ scores)
{
    __shared__ int hist[TT * NSUB];
    __shared__ int base[TT];
    __shared__ int cur[TT * NSUB];

    const int tid = threadIdx.x;
    const int sub = tid & (NSUB - 1);

    for (int i = tid; i < TT * NSUB; i += 1024) hist[i] = 0;
    __syncthreads();

    for (int p = tid; p < PPP; p += 1024) {
        atomicAdd(&hist[(len[p] - 1) * NSUB + sub], 1);
        scores[p] = 0.f;
    }
    __syncthreads();

    if (tid == 0) {
        int ofs = 0;
        for (int l = TT - 1; l >= 0; l--) {     // descending lengths
            base[l] = ofs;
            int tot = 0;
            for (int s = 0; s < NSUB; s++) tot += hist[l * NSUB + s];
            ofs += tot;
        }
    }
    __syncthreads();

    if (tid < TT * NSUB) {
        int l = tid / NSUB, s = tid % NSUB;
        int ofs = base[l];
        for (int q = 0; q < s; q++) ofs += hist[l * NSUB + q];
        cur[tid] = ofs;
    }
    __syncthreads();

    for (int p = tid; p < PPP; p += 1024) {
        int pos = atomicAdd(&cur[(len[p] - 1) * NSUB + sub], 1);
        order[pos] = p;
    }
}

// ---------------- fused fragment precompute ---------------------------------
// U/W frags get the per-gate activation scale FOLDED IN (i,f,o: -log2e;
// g: -2log2e). slots: [0,16384) ufrag, [16384,32768) wfrag, [32768,38912) pfrag.

__global__ __launch_bounds__(256) void frag_kernel(
    const float* __restrict__ Uf, const float* __restrict__ Ub,
    const float* __restrict__ Wf, const float* __restrict__ Wb,
    const float* __restrict__ proj,
    ushort* __restrict__ Ufrag, ushort* __restrict__ Wfrag,
    ushort* __restrict__ pfrag)
{
    const float gsc[4] = {NLOG2E, NLOG2E, N2LOG2E, NLOG2E};
    int gs = blockIdx.x * 256 + threadIdx.x;     // 0..38911
    if (gs < 16384) {                            // ufrag
        int d = gs >> 13, s = gs & 8191;
        const float* U = d ? Ub : Uf;
        int lane = s & 63, kb = (s >> 6) & 3, g = (s >> 8) & 3, w = s >> 10;
        int krow = kb * 32 + (lane >> 4) * 8;
        int col  = g * 128 + w * 16 + (lane & 15);
        float sc = gsc[g];
        ushort* dst = Ufrag + (size_t)gs * 8;
#pragma unroll
        for (int j = 0; j < 8; j++)
            dst[j] = f2bf(U[(size_t)(krow + j) * 512 + col] * sc);
    } else if (gs < 32768) {                     // wfrag
        int t = gs - 16384;
        int d = t >> 13, s = t & 8191;
        const float* W = d ? Wb : Wf;
        int lane = s & 63, kb = (s >> 6) & 3, nt = s >> 8;
        int krow = kb * 32 + (lane >> 4) * 8;
        int col  = nt * 16 + (lane & 15);
        float sc = gsc[col >> 7];
        ushort* dst = Wfrag + (size_t)t * 8;
#pragma unroll
        for (int j = 0; j < 8; j++)
            dst[j] = f2bf(W[(size_t)(krow + j) * 512 + col] * sc);
    } else {                                     // pfrag (no scaling)
        int s = gs - 32768;                      // 0..6143
        int lane = s & 63;
        int kb = (s >> 6) % 12;
        int nt = s / 768;
        int krow = kb * 32 + (lane >> 4) * 8;
        int col  = nt * 16 + (lane & 15);
        ushort* dst = pfrag + (size_t)s * 8;
#pragma unroll
        for (int j = 0; j < 8; j++)
            dst[j] = f2bf(proj[(size_t)(krow + j) * 128 + col]);
    }
}

// ---------------- Zx = emb @ W + b via MFMA -> bf16 gather layout -----------

__global__ __launch_bounds__(512) void zx_kernel(
    const float* __restrict__ emb,
    const ushort* __restrict__ Wfrag,
    const float* __restrict__ bf, const float* __restrict__ bb,
    ushort* __restrict__ Zall)
{
    const float gsc[4] = {NLOG2E, NLOG2E, N2LOG2E, NLOG2E};
    const int dir = blockIdx.y;
    const ushort* WfD = Wfrag + (size_t)dir * 65536;
    const float* bias = dir ? bb : bf;
    ushort* Z = Zall + (size_t)dir * VNT * 512;

    __shared__ union {
        ushort At[64][HSTR];   // A tile: 64 tokens x 128 k (bf16)
        ushort Zt[64][520];    // C bounce: 64 tokens x 512 cols (bf16)
    } sm;

    const int tid  = threadIdx.x;
    const int w    = tid >> 6;
    const int lane = tid & 63;
    const int quad = lane >> 4;
    const int l    = lane & 15;
    const int tok0 = blockIdx.x * 64;

    {
        const int p = tid >> 3, ch = tid & 7;
        int tok = tok0 + p; if (tok > VNT - 1) tok = VNT - 1;
        const float4* src = (const float4*)(emb + (size_t)tok * 128 + ch * 16);
        ushort v[16];
#pragma unroll
        for (int q = 0; q < 4; q++) {
            float4 f = src[q];
            v[q * 4 + 0] = f2bf(f.x); v[q * 4 + 1] = f2bf(f.y);
            v[q * 4 + 2] = f2bf(f.z); v[q * 4 + 3] = f2bf(f.w);
        }
        *(int4*)&sm.At[p][ch * 16]     = *(const int4*)&v[0];
        *(int4*)&sm.At[p][ch * 16 + 8] = *(const int4*)&v[8];
    }

    short8 bq[4][4];   // [nt4][kb]
#pragma unroll
    for (int nt4 = 0; nt4 < 4; nt4++)
#pragma unroll
        for (int kb = 0; kb < 4; kb++)
            bq[nt4][kb] = *(const short8*)(WfD + (size_t)(((w * 4 + nt4) * 4 + kb) * 64 + lane) * 8);

    __syncthreads();

    float4v acc[4][4];     // [mt][nt4]
#pragma unroll
    for (int mt = 0; mt < 4; mt++)
#pragma unroll
        for (int nt4 = 0; nt4 < 4; nt4++) {
            float4v z4 = {0.f, 0.f, 0.f, 0.f};
            acc[mt][nt4] = z4;
        }

#pragma unroll
    for (int kb = 0; kb < 4; kb++) {
        short8 af[4];
#pragma unroll
        for (int mt = 0; mt < 4; mt++)
            af[mt] = *(const short8*)&sm.At[mt * 16 + l][kb * 32 + quad * 8];
#pragma unroll
        for (int nt4 = 0; nt4 < 4; nt4++)
#pragma unroll
            for (int mt = 0; mt < 4; mt++)
                acc[mt][nt4] = __builtin_amdgcn_mfma_f32_16x16x32_bf16(
                    af[mt], bq[nt4][kb], acc[mt][nt4], 0, 0, 0);
    }

    float bv[4];
#pragma unroll
    for (int nt4 = 0; nt4 < 4; nt4++) {
        int col = (w * 4 + nt4) * 16 + l;
        bv[nt4] = bias[col] * gsc[col >> 7];
    }

    __syncthreads();   // all At reads done; union switches to Zt

#pragma unroll
    for (int mt = 0; mt < 4; mt++)
#pragma unroll
        for (int r = 0; r < 4; r++) {
            const int p = mt * 16 + quad * 4 + r;
#pragma unroll
            for (int nt4 = 0; nt4 < 4; nt4++)
                sm.Zt[p][(w * 4 + nt4) * 16 + l] = f2bf(acc[mt][nt4][r] + bv[nt4]);
        }
    __syncthreads();

#pragma unroll
    for (int i = 0; i < 16; i++) {
        int s = i * 512 + tid;          // 0..8191
        int pt = s >> 7;                // token row 0..63
        int u  = s & 127;
        int tok = tok0 + pt;
        if (tok < VNT) {
            ushort v[4];
#pragma unroll
            for (int g = 0; g < 4; g++)
                v[g] = sm.Zt[pt][g * 128 + u];
            *(uint2*)(Z + (size_t)tok * 512 + u * 4) = *(const uint2*)v;
        }
    }
}

// ---------------- MFMA LSTM (32 paths/block, zv pipelined) ------------------
// (512,2): VGPR 88, no spill, 2 blocks/CU — verified best config (R12/R15).
// (512,6) forced VGPR=40 -> 527MB spill, 3.6x regression (R14). Do not raise.

__global__ __launch_bounds__(512, 2) void lstm_kernel(
    const ushort* __restrict__ Zall,
    const ushort* __restrict__ Ufrag,
    const int* __restrict__ path_elements, const int* __restrict__ path_lengths,
    const int* __restrict__ order,
    ushort* __restrict__ h_out)   // bf16 [2][P][128]
{
    const int dir = blockIdx.y;
    const ushort* ZxD = Zall + (size_t)dir * VNT * 512;
    const ushort* UfD = Ufrag + (size_t)dir * 65536;

    __shared__ ushort hp[2][PB][HSTR]; // bf16 h planes (A-layout)
    __shared__ int s_tok[TT][PB];      // pre-shifted byte offsets (tok<<10)
    __shared__ int s_pid[PB];
    __shared__ int s_len[PB];

    const int tid  = threadIdx.x;
    const int w    = tid >> 6;         // wave 0..7
    const int lane = tid & 63;
    const int quad = lane >> 4;
    const int l    = lane & 15;

    if (tid < PB) {
        int idx = blockIdx.x * PB + tid;
        if (idx > PPP - 1) idx = PPP - 1;
        int pid = order[idx];
        s_pid[tid] = pid;
        s_len[tid] = path_lengths[pid];
    }
    for (int i = tid; i < PB * HSTR; i += 512) ((uint*)&hp[0][0][0])[i] = 0;
    __syncthreads();

    for (int i = tid; i < PB * TT; i += 512) {
        int p = i & (PB - 1), t = i >> 5;
        s_tok[t][p] = path_elements[(size_t)s_pid[p] * TT + t] << 10;  // *1024B
    }

    short8 bfrag[4][4];
#pragma unroll
    for (int g = 0; g < 4; g++)
#pragma unroll
        for (int kb = 0; kb < 4; kb++)
            bfrag[g][kb] = *(const short8*)(UfD + (size_t)(((w * 4 + g) * 4 + kb) * 64 + lane) * 8);

    __syncthreads();

    const int maxLen = s_len[0];       // descending sort
    const int myoff  = (w * 16 + l) * 8;
    const char* Zbase = (const char*)ZxD;

    // min length over my 8 rows (largest p I own -> shortest path)
    int lenMin = s_len[16 + quad * 4 + 3];

    float c_st[8];
#pragma unroll
    for (int i = 0; i < 8; i++) c_st[i] = 0.f;

    uint2 zvA[8], zvB[8];
    {
        const int t0 = dir ? (maxLen - 1) : 0;
#pragma unroll
        for (int mt = 0; mt < 2; mt++)
#pragma unroll
            for (int r = 0; r < 4; r++) {
                int off = s_tok[t0][mt * 16 + quad * 4 + r];
                zvA[mt * 4 + r] = *(const uint2*)(Zbase + off + myoff);
            }
    }

    auto stepBody = [&](int step, uint2 (&zvC)[8], uint2 (&zvN)[8]) {
        const int cu = step & 1, nx = cu ^ 1;
        const int t = dir ? (maxLen - 1 - step) : step;

        // acc preload: C = Zx contribution (bf16->f32), arrived last step
        float4v acc[2][4];             // [mt][g]
#pragma unroll
        for (int mt = 0; mt < 2; mt++)
#pragma unroll
            for (int r = 0; r < 4; r++) {
                const uint2 z2 = zvC[mt * 4 + r];
                acc[mt][0][r] = bf2f((ushort)(z2.x & 0xffff));
                acc[mt][1][r] = bf2f((ushort)(z2.x >> 16));
                acc[mt][2][r] = bf2f((ushort)(z2.y & 0xffff));
                acc[mt][3][r] = bf2f((ushort)(z2.y >> 16));
            }

        // prefetch next step's Zx (covered by MFMA + gating + barrier)
        {
            const int stepn = (step + 1 < maxLen) ? step + 1 : step;
            const int tn = dir ? (maxLen - 1 - stepn) : stepn;
#pragma unroll
            for (int mt = 0; mt < 2; mt++)
#pragma unroll
                for (int r = 0; r < 4; r++) {
                    int off = s_tok[tn][mt * 16 + quad * 4 + r];
                    zvN[mt * 4 + r] = *(const uint2*)(Zbase + off + myoff);
                }
        }

#pragma unroll
        for (int kb = 0; kb < 4; kb++) {
            short8 af[2];
#pragma unroll
            for (int mt = 0; mt < 2; mt++)
                af[mt] = *(const short8*)&hp[cu][mt * 16 + l][kb * 32 + quad * 8];
#pragma unroll
            for (int g = 0; g < 4; g++)
#pragma unroll
                for (int mt = 0; mt < 2; mt++)
                    acc[mt][g] = __builtin_amdgcn_mfma_f32_16x16x32_bf16(
                        af[mt], bfrag[g][kb], acc[mt][g], 0, 0, 0);
        }

        if (t < lenMin) {
            // fast path: all my 8 paths valid
#pragma unroll
            for (int mt = 0; mt < 2; mt++)
#pragma unroll
                for (int r = 0; r < 4; r++) {
                    const int p = mt * 16 + quad * 4 + r;
                    float ig = fsig_s(acc[mt][0][r]);
                    float fg = fsig_s(acc[mt][1][r]);
                    float gg = ftanh_s(acc[mt][2][r]);
                    float og = fsig_s(acc[mt][3][r]);
                    float cn = fg * c_st[mt * 4 + r] + ig * gg;
                    float hn = og * ftanh(cn);
                    c_st[mt * 4 + r] = cn;
                    hp[nx][p][w * 16 + l] = f2bf(hn);
                }
        } else {
#pragma unroll
            for (int mt = 0; mt < 2; mt++)
#pragma unroll
                for (int r = 0; r < 4; r++) {
                    const int p = mt * 16 + quad * 4 + r;
                    const bool valid = t < s_len[p];
                    const ushort hold = hp[cu][p][w * 16 + l];
                    float ig = fsig_s(acc[mt][0][r]);
                    float fg = fsig_s(acc[mt][1][r]);
                    float gg = ftanh_s(acc[mt][2][r]);
                    float og = fsig_s(acc[mt][3][r]);
                    float cn = fg * c_st[mt * 4 + r] + ig * gg;
                    float hn = og * ftanh(cn);
                    if (valid) c_st[mt * 4 + r] = cn;
                    hp[nx][p][w * 16 + l] = valid ? f2bf(hn) : hold;
                }
        }
        __syncthreads();
    };

    for (int step = 0; step < maxLen; step += 2) {
        stepBody(step, zvA, zvB);
        if (step + 1 < maxLen) stepBody(step + 1, zvB, zvA);
    }

    // epilogue: final plane -> bf16 h_out; thread -> path pg, cols ch*8..+7
    {
        const int fin = maxLen & 1;
        const int pg = tid >> 4;       // 0..31
        const int ch = tid & 15;       // 0..15 -> 8 cols
        ushort* dst = h_out + ((size_t)dir * PPP + s_pid[pg]) * 128 + ch * 8;
        *(int4*)dst = *(const int4*)&hp[fin][pg][ch * 8];
    }
}

// ---------------- MFMA projection + fused attention scores -----------------

__global__ __launch_bounds__(512) void proj_kernel(
    const float* __restrict__ leaf, const ushort* __restrict__ hbuf,
    const ushort* __restrict__ pfrag, const float* __restrict__ att,
    const int* __restrict__ leaf_idxs,
    float* __restrict__ full, float* __restrict__ scores)
{
    __shared__ ushort Vb[64][400];     // bf16, 16B-aligned rows
    __shared__ int s_lidx[64][2];

    const int tid  = threadIdx.x;
    const int w    = tid >> 6;
    const int lane = tid & 63;
    const int quad = lane >> 4;
    const int l    = lane & 15;
    const int p0   = blockIdx.x * 64;

    if (tid < 128) {
        int p = tid >> 1;
        int pg = p0 + p; if (pg > PPP - 1) pg = PPP - 1;
        s_lidx[p][tid & 1] = leaf_idxs[(size_t)pg * 2 + (tid & 1)];
    }
    __syncthreads();

    for (int s = tid; s < 64 * 192; s += 512) {
        int p = s / 192, cp = s % 192;
        int c = cp * 2;
        int pg = p0 + p; if (pg > PPP - 1) pg = PPP - 1;
        uint val;
        if (c < 128) {
            const float* src = leaf + (size_t)s_lidx[p][c >> 6] * 64 + (c & 63);
            float2 f = *(const float2*)src;
            val = (uint)f2bf(f.x) | ((uint)f2bf(f.y) << 16);
        } else {
            const ushort* src = hbuf + ((size_t)(c < 256 ? 0 : 1) * PPP + pg) * 128 + (c & 127);
            val = *(const uint*)src;
        }
        *(uint*)&Vb[p][c] = val;
    }

    short8 bq[12];
#pragma unroll
    for (int kb = 0; kb < 12; kb++)
        bq[kb] = *(const short8*)(pfrag + ((size_t)w * 768 + kb * 64 + lane) * 8);

    __syncthreads();

    float4v acc[4];
#pragma unroll
    for (int mt = 0; mt < 4; mt++) {
        float4v z4 = {0.f, 0.f, 0.f, 0.f};
        acc[mt] = z4;
    }

#pragma unroll
    for (int kb = 0; kb < 12; kb++) {
#pragma unroll
        for (int mt = 0; mt < 4; mt++) {
            short8 af = *(const short8*)&Vb[mt * 16 + l][kb * 32 + quad * 8];
            acc[mt] = __builtin_amdgcn_mfma_f32_16x16x32_bf16(af, bq[kb], acc[mt], 0, 0, 0);
        }
    }

    const int col = w * 16 + l;
    const float attc = att[col];
#pragma unroll
    for (int mt = 0; mt < 4; mt++)
#pragma unroll
        for (int r = 0; r < 4; r++) {
            int row = mt * 16 + quad * 4 + r;
            int pg = p0 + row;
            float v = acc[mt][r];
            if (pg < PPP) full[(size_t)pg * 128 + col] = v;
            float part = v * attc;
            part += __shfl_xor(part, 1);
            part += __shfl_xor(part, 2);
            part += __shfl_xor(part, 4);
            part += __shfl_xor(part, 8);
            if (l == 0 && pg < PPP) atomicAdd(&scores[pg], part);
        }
}

// ---------------- segment softmax + weighted sum (512 threads) --------------

__global__ __launch_bounds__(512) void seg_kernel(
    const float* __restrict__ scores, const float* __restrict__ full,
    const int* __restrict__ seg, float* __restrict__ out)
{
    const int s = blockIdx.x;
    const int tid = threadIdx.x;

    int lo = 0, hi = PPP;
    while (lo < hi) { int mid = (lo + hi) >> 1; if (seg[mid] < s) lo = mid + 1; else hi = mid; }
    const int start = lo;
    lo = start; hi = PPP;
    while (lo < hi) { int mid = (lo + hi) >> 1; if (seg[mid] < s + 1) lo = mid + 1; else hi = mid; }
    const int end = lo;

    if (start >= end) {
        if (tid < 128) out[(size_t)s * 128 + tid] = 0.f;
        return;
    }

    __shared__ float red[512];

    float mx = -1e30f;
    for (int i = start + tid; i < end; i += 512) mx = fmaxf(mx, scores[i]);
    red[tid] = mx; __syncthreads();
    for (int off = 256; off > 0; off >>= 1) {
        if (tid < off) red[tid] = fmaxf(red[tid], red[tid + off]);
        __syncthreads();
    }
    mx = red[0]; __syncthreads();

    float den = 0.f;
    for (int i = start + tid; i < end; i += 512) den += __expf(scores[i] - mx);
    red[tid] = den; __syncthreads();
    for (int off = 256; off > 0; off >>= 1) {
        if (tid < off) red[tid] += red[tid + off];
        __syncthreads();
    }
    den = red[0]; __syncthreads();

    // weighted sum: 4 path-groups x 2-deep ILP (stride 8)
    const int col = tid & 127;
    const int pp  = tid >> 7;         // 0..3
    float a0 = 0.f, a1 = 0.f;
    for (int i = start + pp; i < end; i += 8) {
        a0 = fmaf(__expf(scores[i] - mx), full[(size_t)i * 128 + col], a0);
        int i2 = i + 4;
        if (i2 < end)
            a1 = fmaf(__expf(scores[i2] - mx), full[(size_t)i2 * 128 + col], a1);
    }
    red[tid] = a0 + a1; __syncthreads();
    if (tid < 128)
        out[(size_t)s * 128 + tid] =
            (red[tid] + red[tid + 128] + red[tid + 256] + red[tid + 384]) / den;
}

// ---------------- launch ---------------------------------------------------

extern "C" void kernel_launch(void* const* d_in, const int* in_sizes, int n_in,
                              void* d_out, int out_size, void* d_ws, size_t ws_size,
                              hipStream_t stream) {
    (void)in_sizes; (void)n_in; (void)out_size; (void)ws_size;

    const float* leaf = (const float*)d_in[0];
    const float* emb  = (const float*)d_in[1];
    const float* Wf   = (const float*)d_in[2];
    const float* Uf   = (const float*)d_in[3];
    const float* bf   = (const float*)d_in[4];
    const float* Wb   = (const float*)d_in[5];
    const float* Ub   = (const float*)d_in[6];
    const float* bb   = (const float*)d_in[7];
    const float* proj = (const float*)d_in[8];
    const float* att  = (const float*)d_in[9];
    const int* path_elements = (const int*)d_in[10];
    const int* path_lengths  = (const int*)d_in[11];
    const int* leaf_idxs     = (const int*)d_in[12];
    const int* seg           = (const int*)d_in[13];
    float* out = (float*)d_out;

    char* ws = (char*)d_ws;
    int*    order  = (int*)ws;                         // 80,000 B
    ushort* Zall   = (ushort*)(ws + 81920);            // 20,480,000
    ushort* Ufrag  = (ushort*)(ws + 20561920);         // 262,144
    ushort* pfrag  = (ushort*)(ws + 20824064);         // 98,304
    ushort* Wfrag  = (ushort*)(ws + 20922368);         // 262,144
    ushort* hbuf   = (ushort*)(ws + 21184512);         // 10,240,000 (bf16)
    float*  full   = (float*)(ws + 31424512);          // 10,240,000
    float*  scores = (float*)(ws + 41664512);          // 80,000

    frag_kernel<<<152, 256, 0, stream>>>(Uf, Ub, Wf, Wb, proj,
                                         Ufrag, Wfrag, pfrag);

    sort_kernel<<<1, 1024, 0, stream>>>(path_lengths, order, scores);

    dim3 gz((VNT + 63) / 64, 2);
    zx_kernel<<<gz, 512, 0, stream>>>(emb, Wfrag, bf, bb, Zall);

    dim3 g(PPP / PB, 2);
    lstm_kernel<<<g, 512, 0, stream>>>(Zall, Ufrag, path_elements, path_lengths,
                                       order, hbuf);

    proj_kernel<<<(PPP + 63) / 64, 512, 0, stream>>>(leaf, hbuf, pfrag, att,
                                                     leaf_idxs, full, scores);

    seg_kernel<<<SS, 512, 0, stream>>>(scores, full, seg, out);
}